// Round 3
// baseline (339.963 us; speedup 1.0000x reference)
//
#include <hip/hip_runtime.h>
#include <hip/hip_bf16.h>
#include <stdint.h>

#define B_    4
#define N_    4096
#define FIN   64
#define NPROP 64
#define NFILT 128
#define KSEL  40
#define ROWS  (B_ * N_)
#define SURV_CAP 160
#define SURV_PAD 176

// ---------------- K1: features = x@W_flr + b_flr ; coords = x@W_s + b_s ----
__global__ __launch_bounds__(256) void k1_proj(
    const float* __restrict__ x, const float* __restrict__ Wf, const float* __restrict__ bf,
    const float* __restrict__ Ws, const float* __restrict__ bs,
    float* __restrict__ feat, float4* __restrict__ coords)
{
    int wid  = threadIdx.x >> 6;
    int lane = threadIdx.x & 63;
    int row  = blockIdx.x * 4 + wid;

    float xv = x[row * FIN + lane];
    float acc = bf[lane];
    float c0 = bs[0], c1 = bs[1], c2 = bs[2], c3 = bs[3];
    #pragma unroll 16
    for (int k = 0; k < FIN; ++k) {
        float xk = __shfl(xv, k);
        acc += xk * Wf[k * NPROP + lane];
        float4 w4 = reinterpret_cast<const float4*>(Ws)[k];
        c0 += xk * w4.x; c1 += xk * w4.y; c2 += xk * w4.z; c3 += xk * w4.w;
    }
    feat[row * NPROP + lane] = acc;
    if (lane == 0) coords[row] = make_float4(c0, c1, c2, c3);
}

// ---------------- K2: exact KNN top-40 via certified threshold + rank -----
// One wave per query. Lane L owns candidates j = L*64 + t (t = 0..63).
//  P1: compute 16-bit dist keys (packed 2/VGPR), track lane-min only.
//  P2: tau = 40th smallest of the 64 lane-minima (bitonic sort, 21 stages).
//      Certified: tau >= true 40th-smallest key (block-min bound).
//  P3: compact survivors (key<=tau, ~62 expected) to LDS; exact rank by
//      counting smaller survivors; ranks 1..39 = neighbor set (0 = self).
//  P4: aggregate winners (order-independent max/mean).
__global__ __launch_bounds__(1024, 8) void k2_knn(
    const float4* __restrict__ coords, const float* __restrict__ feat,
    float* __restrict__ aggout)
{
    __shared__ float4   cT[N_];               // 64 KB, transposed: slot p holds point ((p&63)<<6)|(p>>6)
    __shared__ unsigned surv[16][SURV_PAD];   // 11 KB
    __shared__ int      win[16][KSEL];        // 2.5 KB
    int tid  = threadIdx.x;
    int row0 = blockIdx.x * 16;
    int b    = row0 >> 12;
    const float4* cb = coords + (size_t)b * N_;

    // linear LDS writes (conflict-free), scrambled L2-resident global reads
    for (int p = tid; p < N_; p += 1024) {
        int j = ((p & 63) << 6) | (p >> 6);
        cT[p] = cb[j];
    }
    __syncthreads();

    int wid = tid >> 6, lane = tid & 63;
    int row = row0 + wid;
    int i   = row & (N_ - 1);

    float4 q = cT[((i & 63) << 6) | (i >> 6)];
    float ni = q.x * q.x; ni = fmaf(q.y, q.y, ni); ni = fmaf(q.z, q.z, ni); ni = fmaf(q.w, q.w, ni);

    // ---- P1: stream candidates, keep packed 16-bit keys + lane min ----
    unsigned packed[32];
    unsigned minv = 0xFFFFFFFFu;
    #pragma unroll
    for (int t = 0; t < 64; ++t) {
        float4 c = cT[t * 64 + lane];                    // imm-offset ds_read_b128
        float nj = c.x * c.x; nj = fmaf(c.y, c.y, nj); nj = fmaf(c.z, c.z, nj); nj = fmaf(c.w, c.w, nj);
        float dt = q.x * c.x; dt = fmaf(q.y, c.y, dt); dt = fmaf(q.z, c.z, dt); dt = fmaf(q.w, c.w, dt);
        float s  = fmaf(dt, -2.0f, ni + nj);             // >= 0; exactly 0 for self
        unsigned d16 = __float_as_uint(s) >> 16;
        minv = min(minv, (d16 << 16) | (unsigned)t);
        if (t & 1) packed[t >> 1] |= d16 << 16; else packed[t >> 1] = d16;
    }

    // ---- P2: bitonic sort lane minima (full keys), tau = element 39 ----
    unsigned v = minv + ((unsigned)lane << 6);           // low16 = j = lane*64+t
    #pragma unroll
    for (int k = 2; k <= 64; k <<= 1) {
        #pragma unroll
        for (int j2 = k >> 1; j2 >= 1; j2 >>= 1) {
            unsigned o = (unsigned)__shfl_xor((int)v, j2);
            bool keepmin = (((lane & k) == 0) == ((lane & j2) == 0));
            v = keepmin ? min(v, o) : max(v, o);
        }
    }
    unsigned tau = (unsigned)__shfl((int)v, 39);

    // ---- P3a: survivor compaction via ballot + mbcnt ----
    int base2 = 0;
    unsigned idxbase = (unsigned)(lane << 6);
    #pragma unroll
    for (int u = 0; u < 32; ++u) {
        unsigned pk = packed[u];
        unsigned k0 = (pk << 16) | (idxbase + 2u * u);
        unsigned k1 = (pk & 0xFFFF0000u) | (idxbase + 2u * u + 1u);
        {
            bool p0 = (k0 <= tau);
            unsigned long long m = __ballot(p0);
            if (m) {
                int off = __builtin_amdgcn_mbcnt_hi((unsigned)(m >> 32),
                          __builtin_amdgcn_mbcnt_lo((unsigned)m, 0));
                int slot = base2 + off;
                if (p0 && slot < SURV_CAP) surv[wid][slot] = k0;
                base2 += __popcll(m);
            }
        }
        {
            bool p1 = (k1 <= tau);
            unsigned long long m = __ballot(p1);
            if (m) {
                int off = __builtin_amdgcn_mbcnt_hi((unsigned)(m >> 32),
                          __builtin_amdgcn_mbcnt_lo((unsigned)m, 0));
                int slot = base2 + off;
                if (p1 && slot < SURV_CAP) surv[wid][slot] = k1;
                base2 += __popcll(m);
            }
        }
    }
    int S = min(base2, SURV_CAP);
    if (lane < 8) surv[wid][S + lane] = 0xFFFFFFFFu;     // sentinels (pad to x4 reads)
    if (lane == 8) win[wid][KSEL - 1] = 0;               // dummy slot 39 (masked in agg)

    // ---- P3b: exact rank = #smaller survivors; ranks 1..39 -> winners ----
    for (int r = lane; r < S; r += 64) {
        unsigned my = surv[wid][r];
        int cnt = 0;
        int S4 = (S + 3) >> 2;
        for (int s4 = 0; s4 < S4; ++s4) {
            uint4 u4 = *reinterpret_cast<const uint4*>(&surv[wid][4 * s4]);
            cnt += (u4.x < my) + (u4.y < my) + (u4.z < my) + (u4.w < my);
        }
        if (cnt >= 1 && cnt < KSEL) win[wid][cnt - 1] = (int)(my & 0xFFFFu);
    }

    // ---- P4: aggregate 39 winners (4-wide batched, masked tail) ----
    float mx = -3.4e38f, sm = 0.0f;
    const float* fb = feat + (size_t)b * N_ * NPROP + lane;
    #pragma unroll
    for (int u = 0; u < KSEL / 4; ++u) {
        int4 jv = *reinterpret_cast<const int4*>(&win[wid][4 * u]);
        #pragma unroll
        for (int e = 0; e < 4; ++e) {
            if (4 * u + e > KSEL - 2) break;             // compile-time: skips only slot 39
            int j = (e == 0) ? jv.x : (e == 1) ? jv.y : (e == 2) ? jv.z : jv.w;
            float4 c = cT[((j & 63) << 6) | (j >> 6)];
            float nj = c.x * c.x; nj = fmaf(c.y, c.y, nj); nj = fmaf(c.z, c.z, nj); nj = fmaf(c.w, c.w, nj);
            float dt = q.x * c.x; dt = fmaf(q.y, c.y, dt); dt = fmaf(q.z, c.z, dt); dt = fmaf(q.w, c.w, dt);
            float d  = fabsf(fmaf(dt, -2.0f, ni + nj));
            float w  = __expf(-10.0f * d);
            float f  = fb[(size_t)j * NPROP];
            float wf = w * f;
            mx = fmaxf(mx, wf);
            sm += wf;
        }
    }
    aggout[(size_t)row * NFILT + lane]      = mx;
    aggout[(size_t)row * NFILT + 64 + lane] = sm * (1.0f / 39.0f);
}

// ---------------- K3: out = [x | max | mean] @ W_out + b_out --------------
__global__ __launch_bounds__(512) void k3_out(
    const float* __restrict__ x, const float* __restrict__ agg,
    const float* __restrict__ Wo, const float* __restrict__ bo,
    float* __restrict__ out)
{
    __shared__ float xa[32 * FIN];    // 8 KB
    __shared__ float ga[32 * NFILT];  // 16 KB
    int tid = threadIdx.x;
    int r0  = blockIdx.x * 32;
    for (int idx = tid; idx < 32 * FIN / 4; idx += 512)
        reinterpret_cast<float4*>(xa)[idx] =
            reinterpret_cast<const float4*>(x + (size_t)r0 * FIN)[idx];
    for (int idx = tid; idx < 32 * NFILT / 4; idx += 512)
        reinterpret_cast<float4*>(ga)[idx] =
            reinterpret_cast<const float4*>(agg + (size_t)r0 * NFILT)[idx];
    __syncthreads();

    int c = tid & 127, rg = tid >> 7;
    float acc[8];
    float bb = bo[c];
    #pragma unroll
    for (int r = 0; r < 8; ++r) acc[r] = bb;

    #pragma unroll 4
    for (int k = 0; k < FIN; k += 4) {
        float w0 = Wo[(k + 0) * NFILT + c];
        float w1 = Wo[(k + 1) * NFILT + c];
        float w2 = Wo[(k + 2) * NFILT + c];
        float w3 = Wo[(k + 3) * NFILT + c];
        #pragma unroll
        for (int r = 0; r < 8; ++r) {
            float4 xv = *reinterpret_cast<const float4*>(&xa[(rg * 8 + r) * FIN + k]);
            acc[r] = fmaf(xv.x, w0, fmaf(xv.y, w1, fmaf(xv.z, w2, fmaf(xv.w, w3, acc[r]))));
        }
    }
    #pragma unroll 4
    for (int k = 0; k < NFILT; k += 4) {
        float w0 = Wo[(FIN + k + 0) * NFILT + c];
        float w1 = Wo[(FIN + k + 1) * NFILT + c];
        float w2 = Wo[(FIN + k + 2) * NFILT + c];
        float w3 = Wo[(FIN + k + 3) * NFILT + c];
        #pragma unroll
        for (int r = 0; r < 8; ++r) {
            float4 gv = *reinterpret_cast<const float4*>(&ga[(rg * 8 + r) * NFILT + k]);
            acc[r] = fmaf(gv.x, w0, fmaf(gv.y, w1, fmaf(gv.z, w2, fmaf(gv.w, w3, acc[r]))));
        }
    }
    #pragma unroll
    for (int r = 0; r < 8; ++r)
        out[(size_t)(r0 + rg * 8 + r) * NFILT + c] = acc[r];
}

extern "C" void kernel_launch(void* const* d_in, const int* in_sizes, int n_in,
                              void* d_out, int out_size, void* d_ws, size_t ws_size,
                              hipStream_t stream)
{
    const float* x  = (const float*)d_in[0];
    const float* Wf = (const float*)d_in[1];
    const float* bf = (const float*)d_in[2];
    const float* Ws = (const float*)d_in[3];
    const float* bs = (const float*)d_in[4];
    const float* Wo = (const float*)d_in[5];
    const float* bo = (const float*)d_in[6];
    float* out = (float*)d_out;

    float*  feat   = (float*)d_ws;                                        // 4 MB
    float4* coords = (float4*)((char*)d_ws + (size_t)ROWS * NPROP * 4);   // 256 KB

    k1_proj<<<ROWS / 4,  256, 0, stream>>>(x, Wf, bf, Ws, bs, feat, coords);
    k2_knn <<<ROWS / 16, 1024, 0, stream>>>(coords, feat, out);
    k3_out <<<ROWS / 32, 512, 0, stream>>>(x, out, Wo, bo, out);
}

// Round 4
// 127.009 us; speedup vs baseline: 2.6767x; 2.6767x over previous
//
#include <hip/hip_runtime.h>
#include <hip/hip_bf16.h>
#include <stdint.h>

#define B_    4
#define N_    4096
#define FIN   64
#define NPROP 64
#define NFILT 128
#define KSEL  40
#define ROWS  (B_ * N_)
#define SURV_CAP 160
#define SURV_PAD 176

// ---------------- K1: features = x@W_flr + b_flr ; coords = x@W_s + b_s ----
__global__ __launch_bounds__(256) void k1_proj(
    const float* __restrict__ x, const float* __restrict__ Wf, const float* __restrict__ bf,
    const float* __restrict__ Ws, const float* __restrict__ bs,
    float* __restrict__ feat, float4* __restrict__ coords)
{
    int wid  = threadIdx.x >> 6;
    int lane = threadIdx.x & 63;
    int row  = blockIdx.x * 4 + wid;

    float xv = x[row * FIN + lane];
    float acc = bf[lane];
    float c0 = bs[0], c1 = bs[1], c2 = bs[2], c3 = bs[3];
    #pragma unroll 16
    for (int k = 0; k < FIN; ++k) {
        float xk = __shfl(xv, k);
        acc += xk * Wf[k * NPROP + lane];
        float4 w4 = reinterpret_cast<const float4*>(Ws)[k];
        c0 += xk * w4.x; c1 += xk * w4.y; c2 += xk * w4.z; c3 += xk * w4.w;
    }
    feat[row * NPROP + lane] = acc;
    if (lane == 0) coords[row] = make_float4(c0, c1, c2, c3);
}

// ---------------- K2: exact KNN top-40, certified threshold, NO key storage
// One wave per query. Lane L owns candidates j = L*64 + t.
//  P1: stream, track lane-min key only (~12 VALU/candidate, nothing stored).
//  P2: bitonic-sort 64 lane minima (21 shfl_xor) -> tau = 40th smallest.
//      Certified upper bound: the 40 smallest lane minima are 40 distinct
//      keys <= tau, so true 40th-smallest key <= tau.
//  P3: re-stream, recompute keys, ballot-compact survivors (key<=tau,
//      E[S]~61) to LDS; exact rank = #smaller survivors; ranks 1..39 = set.
//  P4: aggregate winners (max / mean are order-independent).
__global__ __launch_bounds__(1024, 8) void k2_knn(
    const float4* __restrict__ coords, const float* __restrict__ feat,
    float* __restrict__ aggout)
{
    __shared__ float4   cT[N_];               // 64 KB, slot p holds point ((p&63)<<6)|(p>>6)
    __shared__ unsigned surv[16][SURV_PAD];   // 11 KB
    __shared__ int      win[16][KSEL];        // 2.5 KB
    int tid  = threadIdx.x;
    int row0 = blockIdx.x * 16;
    int b    = row0 >> 12;
    const float4* cb = coords + (size_t)b * N_;

    // linear LDS writes (conflict-free); scrambled L2-resident global reads
    for (int p = tid; p < N_; p += 1024) {
        int j = ((p & 63) << 6) | (p >> 6);
        cT[p] = cb[j];
    }
    __syncthreads();

    int wid = tid >> 6, lane = tid & 63;
    int row = row0 + wid;
    int i   = row & (N_ - 1);

    float4 q = cT[((i & 63) << 6) | (i >> 6)];
    float ni = q.x * q.x; ni = fmaf(q.y, q.y, ni); ni = fmaf(q.z, q.z, ni); ni = fmaf(q.w, q.w, ni);

    // ---- P1: lane-min key only ----
    unsigned minv = 0xFFFFFFFFu;
    #pragma unroll 8
    for (int t = 0; t < 64; ++t) {
        float4 c = cT[t * 64 + lane];                    // imm-offset ds_read_b128
        float nj = c.x * c.x; nj = fmaf(c.y, c.y, nj); nj = fmaf(c.z, c.z, nj); nj = fmaf(c.w, c.w, nj);
        float dt = q.x * c.x; dt = fmaf(q.y, c.y, dt); dt = fmaf(q.z, c.z, dt); dt = fmaf(q.w, c.w, dt);
        float s  = fmaf(dt, -2.0f, ni + nj);             // >= 0; exactly 0 for self
        unsigned key = (__float_as_uint(s) & 0xFFFF0000u) | (unsigned)t;
        minv = min(minv, key);
    }

    // ---- P2: bitonic sort of lane minima, tau = element 39 ----
    unsigned v = minv + ((unsigned)lane << 6);           // low bits -> j = lane*64+t
    #pragma unroll
    for (int k = 2; k <= 64; k <<= 1) {
        #pragma unroll
        for (int j2 = k >> 1; j2 >= 1; j2 >>= 1) {
            unsigned o = (unsigned)__shfl_xor((int)v, j2);
            bool keepmin = (((lane & k) == 0) == ((lane & j2) == 0));
            v = keepmin ? min(v, o) : max(v, o);
        }
    }
    unsigned tau = (unsigned)__shfl((int)v, 39);

    // ---- P3: re-stream, compact survivors, then exact rank ----
    int base2 = 0;
    #pragma unroll 4
    for (int t = 0; t < 64; ++t) {
        float4 c = cT[t * 64 + lane];
        float nj = c.x * c.x; nj = fmaf(c.y, c.y, nj); nj = fmaf(c.z, c.z, nj); nj = fmaf(c.w, c.w, nj);
        float dt = q.x * c.x; dt = fmaf(q.y, c.y, dt); dt = fmaf(q.z, c.z, dt); dt = fmaf(q.w, c.w, dt);
        float s  = fmaf(dt, -2.0f, ni + nj);
        unsigned key = (__float_as_uint(s) & 0xFFFF0000u) | (unsigned)(lane * 64 + t);
        bool pr = (key <= tau);
        unsigned long long m = __ballot(pr);
        if (m) {
            int off = __builtin_amdgcn_mbcnt_hi((unsigned)(m >> 32),
                      __builtin_amdgcn_mbcnt_lo((unsigned)m, 0));
            int slot = base2 + off;
            if (pr && slot < SURV_CAP) surv[wid][slot] = key;
            base2 += __popcll(m);
        }
    }
    int S = min(base2, SURV_CAP);
    if (lane < 8) surv[wid][S + lane] = 0xFFFFFFFFu;     // sentinels (pad to x4 reads)
    if (lane == 8) win[wid][KSEL - 1] = 0;               // dummy slot 39 (masked in P4)

    for (int r = lane; r < S; r += 64) {
        unsigned my = surv[wid][r];
        int cnt = 0;
        int S4 = (S + 3) >> 2;
        for (int s4 = 0; s4 < S4; ++s4) {
            uint4 u4 = *reinterpret_cast<const uint4*>(&surv[wid][4 * s4]);
            cnt += (u4.x < my) + (u4.y < my) + (u4.z < my) + (u4.w < my);
        }
        if (cnt >= 1 && cnt < KSEL) win[wid][cnt - 1] = (int)(my & 0xFFFFu);
    }

    // ---- P4: aggregate 39 winners ----
    float mx = -3.4e38f, sm = 0.0f;
    const float* fb = feat + (size_t)b * N_ * NPROP + lane;
    #pragma unroll 2
    for (int u = 0; u < KSEL / 4; ++u) {
        int4 jv = *reinterpret_cast<const int4*>(&win[wid][4 * u]);
        #pragma unroll
        for (int e = 0; e < 4; ++e) {
            if (4 * u + e > KSEL - 2) break;             // compile-time: skips only slot 39
            int j = (e == 0) ? jv.x : (e == 1) ? jv.y : (e == 2) ? jv.z : jv.w;
            float4 c = cT[((j & 63) << 6) | (j >> 6)];
            float nj = c.x * c.x; nj = fmaf(c.y, c.y, nj); nj = fmaf(c.z, c.z, nj); nj = fmaf(c.w, c.w, nj);
            float dt = q.x * c.x; dt = fmaf(q.y, c.y, dt); dt = fmaf(q.z, c.z, dt); dt = fmaf(q.w, c.w, dt);
            float d  = fabsf(fmaf(dt, -2.0f, ni + nj));
            float w  = __expf(-10.0f * d);
            float f  = fb[(size_t)j * NPROP];
            float wf = w * f;
            mx = fmaxf(mx, wf);
            sm += wf;
        }
    }
    aggout[(size_t)row * NFILT + lane]      = mx;
    aggout[(size_t)row * NFILT + 64 + lane] = sm * (1.0f / 39.0f);
}

// ---------------- K3: out = [x | max | mean] @ W_out + b_out --------------
__global__ __launch_bounds__(512) void k3_out(
    const float* __restrict__ x, const float* __restrict__ agg,
    const float* __restrict__ Wo, const float* __restrict__ bo,
    float* __restrict__ out)
{
    __shared__ float xa[32 * FIN];    // 8 KB
    __shared__ float ga[32 * NFILT];  // 16 KB
    int tid = threadIdx.x;
    int r0  = blockIdx.x * 32;
    for (int idx = tid; idx < 32 * FIN / 4; idx += 512)
        reinterpret_cast<float4*>(xa)[idx] =
            reinterpret_cast<const float4*>(x + (size_t)r0 * FIN)[idx];
    for (int idx = tid; idx < 32 * NFILT / 4; idx += 512)
        reinterpret_cast<float4*>(ga)[idx] =
            reinterpret_cast<const float4*>(agg + (size_t)r0 * NFILT)[idx];
    __syncthreads();

    int c = tid & 127, rg = tid >> 7;
    float acc[8];
    float bb = bo[c];
    #pragma unroll
    for (int r = 0; r < 8; ++r) acc[r] = bb;

    #pragma unroll 4
    for (int k = 0; k < FIN; k += 4) {
        float w0 = Wo[(k + 0) * NFILT + c];
        float w1 = Wo[(k + 1) * NFILT + c];
        float w2 = Wo[(k + 2) * NFILT + c];
        float w3 = Wo[(k + 3) * NFILT + c];
        #pragma unroll
        for (int r = 0; r < 8; ++r) {
            float4 xv = *reinterpret_cast<const float4*>(&xa[(rg * 8 + r) * FIN + k]);
            acc[r] = fmaf(xv.x, w0, fmaf(xv.y, w1, fmaf(xv.z, w2, fmaf(xv.w, w3, acc[r]))));
        }
    }
    #pragma unroll 4
    for (int k = 0; k < NFILT; k += 4) {
        float w0 = Wo[(FIN + k + 0) * NFILT + c];
        float w1 = Wo[(FIN + k + 1) * NFILT + c];
        float w2 = Wo[(FIN + k + 2) * NFILT + c];
        float w3 = Wo[(FIN + k + 3) * NFILT + c];
        #pragma unroll
        for (int r = 0; r < 8; ++r) {
            float4 gv = *reinterpret_cast<const float4*>(&ga[(rg * 8 + r) * NFILT + k]);
            acc[r] = fmaf(gv.x, w0, fmaf(gv.y, w1, fmaf(gv.z, w2, fmaf(gv.w, w3, acc[r]))));
        }
    }
    #pragma unroll
    for (int r = 0; r < 8; ++r)
        out[(size_t)(r0 + rg * 8 + r) * NFILT + c] = acc[r];
}

extern "C" void kernel_launch(void* const* d_in, const int* in_sizes, int n_in,
                              void* d_out, int out_size, void* d_ws, size_t ws_size,
                              hipStream_t stream)
{
    const float* x  = (const float*)d_in[0];
    const float* Wf = (const float*)d_in[1];
    const float* bf = (const float*)d_in[2];
    const float* Ws = (const float*)d_in[3];
    const float* bs = (const float*)d_in[4];
    const float* Wo = (const float*)d_in[5];
    const float* bo = (const float*)d_in[6];
    float* out = (float*)d_out;

    float*  feat   = (float*)d_ws;                                        // 4 MB
    float4* coords = (float4*)((char*)d_ws + (size_t)ROWS * NPROP * 4);   // 256 KB

    k1_proj<<<ROWS / 4,  256, 0, stream>>>(x, Wf, bf, Ws, bs, feat, coords);
    k2_knn <<<ROWS / 16, 1024, 0, stream>>>(coords, feat, out);
    k3_out <<<ROWS / 32, 512, 0, stream>>>(x, out, Wo, bo, out);
}